// Round 6
// baseline (2330.952 us; speedup 1.0000x reference)
//
#include <hip/hip_runtime.h>
#include <hip/hip_bf16.h>

// out = x @ (qw*scale)^T + b  => GEMM M=8192, N=8192, K=2048, bf16 MFMA.
// R6: back to verified 16x16x32 fragments (R5's 32x32 pattern bank-conflicted).
// New structure: BK=32, ring-2 LDS (64 KiB/block) -> 2 blocks/CU (16 waves)
// so the two blocks drift and one block's MFMA overlaps the other's LDS reads
// (the serialized-window model predicted and matched R4's 48% MfmaUtil).
// One vmcnt(0)+barrier per K-tile (drain distance ~ full tile >> HBM latency).

#define M_DIM 8192
#define N_DIM 8192
#define K_DIM 2048
#define NTT   (K_DIM / 32)   // 64 K-tiles (BK=32)

typedef __attribute__((ext_vector_type(8))) short bf16x8;
typedef __attribute__((ext_vector_type(4))) float f32x4;

__device__ __forceinline__ ushort f2bf(float f) {
    union { float f; unsigned int u; } v; v.f = f;
    unsigned int u = v.u;
    return (ushort)((u + 0x7fffu + ((u >> 16) & 1u)) >> 16);  // RNE
}

// Fused convert: chunks [0, n4) = x (fp32->bf16), [n4, 2*n4) = w (int->bf16).
__global__ void cvt_kernel(const float* __restrict__ x, const int* __restrict__ w,
                           ushort* __restrict__ xb, ushort* __restrict__ wb, int n4) {
    int i = blockIdx.x * blockDim.x + threadIdx.x;
    if (i < n4) {
        const float4 v = reinterpret_cast<const float4*>(x)[i];
        ushort4 r;
        r.x = f2bf(v.x); r.y = f2bf(v.y); r.z = f2bf(v.z); r.w = f2bf(v.w);
        reinterpret_cast<ushort4*>(xb)[i] = r;
    } else {
        int j = i - n4;
        const int4 v = reinterpret_cast<const int4*>(w)[j];
        ushort4 r;
        r.x = f2bf((float)v.x); r.y = f2bf((float)v.y);
        r.z = f2bf((float)v.z); r.w = f2bf((float)v.w);
        reinterpret_cast<ushort4*>(wb)[j] = r;
    }
}

// 256x256 tile, BK=32, 512 threads (8 waves 2Mx4N, wave tile 128x64).
// LDS: 2 ring buffers x (A,B) x [256 rows][32 k] bf16 = 64 KiB -> 2 blocks/CU.
// Swizzle (verified 0-conflict R2-R4): stored slot = granule ^ ((row>>1)&3),
// staged via pre-swizzled global source + linear LDS dest (rule 21).
// Per K-tile t (buf b=t&1): {ds_read af(mh0)+bf; stage A(t+1); MFMA16(0);
// ds_read af(mh1); stage B(t+1); MFMA16(1); vmcnt(0); barrier}.
// WAR: stage(t+1) hits buf b^1 whose readers finished at barrier end-of-(t-1).
// RAW: stage(t) drained by vmcnt(0)+barrier at end-of-(t-1).
__global__ __launch_bounds__(512, 4) void gemm_bf16_kernel(
    const ushort* __restrict__ A,   // [M][K] bf16
    const ushort* __restrict__ B,   // [N][K] bf16
    const float* __restrict__ scale_p,
    const float* __restrict__ bias,
    float* __restrict__ C)          // [M][N] fp32
{
    __shared__ __align__(16) ushort lds[2][2][8192];   // [buf][A/B][256*32]

    const int tid  = threadIdx.x;
    const int lane = tid & 63;
    const int wave = tid >> 6;
    const int wr = wave >> 2;        // 0..1 (128-row M half)
    const int wc = wave & 3;         // 0..3 (64-col N quarter)
    const int bm = blockIdx.y;
    const int bn = blockIdx.x;

    const ushort* gA = A + (size_t)(bm * 256) * K_DIM;
    const ushort* gB = B + (size_t)(bn * 256) * K_DIM;

    const int sr = tid >> 2;                       // 0..127
    const int sg = (tid & 3) ^ ((tid >> 3) & 3);   // pre-swizzled source granule
    const ushort* sA0 = gA + (size_t)sr * K_DIM + sg * 8;
    const ushort* sA1 = gA + (size_t)(sr + 128) * K_DIM + sg * 8;
    const ushort* sB0 = gB + (size_t)sr * K_DIM + sg * 8;
    const ushort* sB1 = gB + (size_t)(sr + 128) * K_DIM + sg * 8;

#define GLDS(src, dst) __builtin_amdgcn_global_load_lds( \
    (const __attribute__((address_space(1))) unsigned int*)(src), \
    (__attribute__((address_space(3))) unsigned int*)(dst), 16, 0, 0)

#define STAGE_A(buf, kt) do { \
    GLDS(sA0 + (kt) * 32, &lds[buf][0][tid * 8]); \
    GLDS(sA1 + (kt) * 32, &lds[buf][0][tid * 8 + 4096]); \
} while (0)

#define STAGE_B(buf, kt) do { \
    GLDS(sB0 + (kt) * 32, &lds[buf][1][tid * 8]); \
    GLDS(sB1 + (kt) * 32, &lds[buf][1][tid * 8 + 4096]); \
} while (0)

    f32x4 acc[8][4];
#pragma unroll
    for (int m = 0; m < 8; ++m)
#pragma unroll
        for (int n = 0; n < 4; ++n)
            acc[m][n] = (f32x4){0.f, 0.f, 0.f, 0.f};

    const int lr   = lane & 15;
    const int swzC = ((lane >> 4) ^ ((lane >> 1) & 3)) << 4;
    const int offA = (wr * 128 + lr) * 64 + swzC;   // + mh*4096 + m*1024
    const int offB = (wc * 64  + lr) * 64 + swzC;   // + n*1024

    bf16x8 af[4], bfr[4];

#define DS_AF(buf, mh) do { \
    const char* _p = (const char*)&lds[buf][0][0] + offA + (mh) * 4096; \
    af[0] = *(const bf16x8*)(_p);        af[1] = *(const bf16x8*)(_p + 1024); \
    af[2] = *(const bf16x8*)(_p + 2048); af[3] = *(const bf16x8*)(_p + 3072); \
} while (0)

#define DS_BF(buf) do { \
    const char* _p = (const char*)&lds[buf][1][0] + offB; \
    bfr[0] = *(const bf16x8*)(_p);        bfr[1] = *(const bf16x8*)(_p + 1024); \
    bfr[2] = *(const bf16x8*)(_p + 2048); bfr[3] = *(const bf16x8*)(_p + 3072); \
} while (0)

#define MFMA16(mh) do { \
    _Pragma("unroll") \
    for (int _m = 0; _m < 4; ++_m) \
        _Pragma("unroll") \
        for (int _n = 0; _n < 4; ++_n) \
            acc[(mh) * 4 + _m][_n] = __builtin_amdgcn_mfma_f32_16x16x32_bf16( \
                af[_m], bfr[_n], acc[(mh) * 4 + _m][_n], 0, 0, 0); \
} while (0)

#define BARRIER() do { __builtin_amdgcn_s_barrier(); asm volatile("" ::: "memory"); } while (0)

// One K-tile: reads from buf b, stages tile (kt+1) into buf b^1.
#define TILE(b, SA, SB) do { \
    DS_AF(b, 0); DS_BF(b); \
    SA; \
    __builtin_amdgcn_s_setprio(1); MFMA16(0); __builtin_amdgcn_s_setprio(0); \
    DS_AF(b, 1); \
    SB; \
    __builtin_amdgcn_s_setprio(1); MFMA16(1); __builtin_amdgcn_s_setprio(0); \
    asm volatile("s_waitcnt vmcnt(0)" ::: "memory"); \
    BARRIER(); \
} while (0)

    // Prologue: stage tile 0, drain, sync.
    STAGE_A(0, 0); STAGE_B(0, 0);
    asm volatile("s_waitcnt vmcnt(0)" ::: "memory");
    BARRIER();

#pragma unroll 1
    for (int it = 0; it < NTT / 2 - 1; ++it) {
        const int t = 2 * it;
        TILE(0, STAGE_A(1, t + 1), STAGE_B(1, t + 1));
        TILE(1, STAGE_A(0, t + 2), STAGE_B(0, t + 2));
    }
    // t = NTT-2: stage last tile; t = NTT-1: no stage, no trailing sync.
    TILE(0, STAGE_A(1, NTT - 1), STAGE_B(1, NTT - 1));
    {
        DS_AF(1, 0); DS_BF(1);
        __builtin_amdgcn_s_setprio(1); MFMA16(0); __builtin_amdgcn_s_setprio(0);
        DS_AF(1, 1);
        __builtin_amdgcn_s_setprio(1); MFMA16(1); __builtin_amdgcn_s_setprio(0);
    }

#undef TILE
#undef BARRIER
#undef MFMA16
#undef DS_BF
#undef DS_AF
#undef STAGE_B
#undef STAGE_A
#undef GLDS

    // Epilogue: C/D layout col = lane&15, row = (lane>>4)*4 + j (verified R1-R4)
    const float s = scale_p[0];
#pragma unroll
    for (int n = 0; n < 4; ++n) {
        const int col = bn * 256 + wc * 64 + n * 16 + lr;
        const float bb = bias[col];
#pragma unroll
        for (int m = 0; m < 8; ++m) {
            const int row0 = bm * 256 + wr * 128 + m * 16 + (lane >> 4) * 4;
#pragma unroll
            for (int j = 0; j < 4; ++j)
                C[(size_t)(row0 + j) * N_DIM + col] = acc[m][n][j] * s + bb;
        }
    }
}

// Correctness-insurance fallback if ws_size < 64 MiB (should not trigger).
__global__ void naive_fallback(const float* __restrict__ x, const int* __restrict__ w,
                               const float* __restrict__ scale, const float* __restrict__ bias,
                               float* __restrict__ out) {
    size_t i = (size_t)blockIdx.x * blockDim.x + threadIdx.x;
    int m = (int)(i / N_DIM);
    int n = (int)(i % N_DIM);
    const float* xr = x + (size_t)m * K_DIM;
    const int*   wrw = w + (size_t)n * K_DIM;
    float acc = 0.f;
    for (int k = 0; k < K_DIM; ++k) acc += xr[k] * (float)wrw[k];
    out[i] = acc * scale[0] + bias[n];
}

extern "C" void kernel_launch(void* const* d_in, const int* in_sizes, int n_in,
                              void* d_out, int out_size, void* d_ws, size_t ws_size,
                              hipStream_t stream) {
    const float* x     = (const float*)d_in[0];
    const int*   qw    = (const int*)d_in[1];
    const float* scale = (const float*)d_in[2];
    const float* bias  = (const float*)d_in[3];
    float* out = (float*)d_out;

    const size_t elems = (size_t)M_DIM * K_DIM;          // 16,777,216
    const size_t need  = elems * 2u * sizeof(ushort);    // 64 MiB

    if (ws_size >= need) {
        ushort* xb = (ushort*)d_ws;
        ushort* wb = xb + elems;
        const int n4 = (int)(elems / 4);
        cvt_kernel<<<(2 * n4) / 256, 256, 0, stream>>>(x, qw, xb, wb, n4);
        dim3 grid(N_DIM / 256, M_DIM / 256);
        gemm_bf16_kernel<<<grid, 512, 0, stream>>>(xb, wb, scale, bias, out);
    } else {
        const size_t total = (size_t)M_DIM * N_DIM;
        naive_fallback<<<(int)(total / 256), 256, 0, stream>>>(x, qw, scale, bias, out);
    }
}

// Round 7
// 273.487 us; speedup vs baseline: 8.5231x; 8.5231x over previous
//
#include <hip/hip_runtime.h>
#include <hip/hip_bf16.h>

// out = x @ (qw*scale)^T + b  => GEMM M=8192, N=8192, K=2048, bf16 MFMA.
// R7 = R4 structure with ONE barrier per phase (post-MFMA barrier removed;
// WAR/RAW re-verified: reads+stage issue pre-barrier, MFMA post-barrier,
// every staged piece's readers complete >=1 barrier before the stage) and
// only 2 vmcnt drains per iteration (uniform vmcnt(4) at p3/p7; m201 cadence).
// R6's lesson: 2 blocks/CU infeasible (acc regs); overlap comes from wave skew.

#define M_DIM 8192
#define N_DIM 8192
#define K_DIM 2048
#define NT    (K_DIM / 64)   // 32 K-tiles (BK=64), 2 per iteration

typedef __attribute__((ext_vector_type(8))) short bf16x8;
typedef __attribute__((ext_vector_type(4))) float f32x4;

__device__ __forceinline__ ushort f2bf(float f) {
    union { float f; unsigned int u; } v; v.f = f;
    unsigned int u = v.u;
    return (ushort)((u + 0x7fffu + ((u >> 16) & 1u)) >> 16);  // RNE
}

// Fused convert: chunks [0, n4) = x (fp32->bf16), [n4, 2*n4) = w (int->bf16).
__global__ void cvt_kernel(const float* __restrict__ x, const int* __restrict__ w,
                           ushort* __restrict__ xb, ushort* __restrict__ wb, int n4) {
    int i = blockIdx.x * blockDim.x + threadIdx.x;
    if (i < n4) {
        const float4 v = reinterpret_cast<const float4*>(x)[i];
        ushort4 r;
        r.x = f2bf(v.x); r.y = f2bf(v.y); r.z = f2bf(v.z); r.w = f2bf(v.w);
        reinterpret_cast<ushort4*>(xb)[i] = r;
    } else {
        int j = i - n4;
        const int4 v = reinterpret_cast<const int4*>(w)[j];
        ushort4 r;
        r.x = f2bf((float)v.x); r.y = f2bf((float)v.y);
        r.z = f2bf((float)v.z); r.w = f2bf((float)v.w);
        reinterpret_cast<ushort4*>(wb)[j] = r;
    }
}

// Piece = [256 rows][32 k] bf16 = 16 KiB, 2 gload_lds/thread. lds[buf][op][kh].
// Stage map (iteration i, tiles t=2i buf0 / t+1 buf1):
//  p0: (1,A,kh1)<-t+1   p1: (1,B,kh1)<-t+1   p2: (0,A,kh0)<-t+2  p3: (0,B,kh0)<-t+2
//  p4: (0,A,kh1)<-t+2   p5: (0,B,kh1)<-t+2   p6: (1,A,kh0)<-t+3  p7: (1,B,kh0)<-t+3
// Reads: p0/p1 buf0 kh0 (mh0/mh1), p2/p3 buf0 kh1, p4/p5 buf1 kh0, p6/p7 buf1 kh1.
// Phase p: {ds_read; stage; [p3/p7: vmcnt(4)]; s_barrier; 16 MFMA}.
// vmcnt(4) at p3 leaves only p2/p3's 4 loads outstanding -> p4..p7 data valid;
// at p7 leaves p6/p7's -> next p0..p3 data valid. Prologue drain likewise (4).
__global__ __launch_bounds__(512, 2) void gemm_bf16_kernel(
    const ushort* __restrict__ A,   // [M][K] bf16
    const ushort* __restrict__ B,   // [N][K] bf16
    const float* __restrict__ scale_p,
    const float* __restrict__ bias,
    float* __restrict__ C)          // [M][N] fp32
{
    __shared__ __align__(16) ushort lds[2][2][2][8192];

    const int tid  = threadIdx.x;
    const int lane = tid & 63;
    const int wave = tid >> 6;
    const int wr = wave >> 2;        // 0..1 (128-row M half)
    const int wc = wave & 3;         // 0..3 (64-col N quarter)
    const int bm = blockIdx.y;
    const int bn = blockIdx.x;

    const ushort* gA = A + (size_t)(bm * 256) * K_DIM;
    const ushort* gB = B + (size_t)(bn * 256) * K_DIM;

    const int sr = tid >> 2;                       // 0..127
    const int sg = (tid & 3) ^ ((tid >> 3) & 3);   // pre-swizzled source granule
    const ushort* sA0 = gA + (size_t)sr * K_DIM + sg * 8;
    const ushort* sA1 = gA + (size_t)(sr + 128) * K_DIM + sg * 8;
    const ushort* sB0 = gB + (size_t)sr * K_DIM + sg * 8;
    const ushort* sB1 = gB + (size_t)(sr + 128) * K_DIM + sg * 8;

#define GLDS(src, dst) __builtin_amdgcn_global_load_lds( \
    (const __attribute__((address_space(1))) unsigned int*)(src), \
    (__attribute__((address_space(3))) unsigned int*)(dst), 16, 0, 0)

#define STAGE_P(buf, op, kh, kt) do { \
    const int _c = (kt) * 64 + (kh) * 32; \
    GLDS(((op) ? sB0 : sA0) + _c, &lds[buf][op][kh][tid * 8]); \
    GLDS(((op) ? sB1 : sA1) + _c, &lds[buf][op][kh][tid * 8 + 4096]); \
} while (0)

    f32x4 acc[8][4];
#pragma unroll
    for (int m = 0; m < 8; ++m)
#pragma unroll
        for (int n = 0; n < 4; ++n)
            acc[m][n] = (f32x4){0.f, 0.f, 0.f, 0.f};

    const int lr   = lane & 15;
    const int swzC = ((lane >> 4) ^ ((lane >> 1) & 3)) << 4;
    const int offA = (wr * 128 + lr) * 64 + swzC;   // + mh*4096 + m*1024
    const int offB = (wc * 64  + lr) * 64 + swzC;   // + n*1024

    bf16x8 af[4], bfr[4];

#define DS_AF(buf, kh, mh) do { \
    const char* _p = (const char*)&lds[buf][0][kh][0] + offA + (mh) * 4096; \
    af[0] = *(const bf16x8*)(_p);        af[1] = *(const bf16x8*)(_p + 1024); \
    af[2] = *(const bf16x8*)(_p + 2048); af[3] = *(const bf16x8*)(_p + 3072); \
} while (0)

#define DS_BF(buf, kh) do { \
    const char* _p = (const char*)&lds[buf][1][kh][0] + offB; \
    bfr[0] = *(const bf16x8*)(_p);        bfr[1] = *(const bf16x8*)(_p + 1024); \
    bfr[2] = *(const bf16x8*)(_p + 2048); bfr[3] = *(const bf16x8*)(_p + 3072); \
} while (0)

#define MFMA16(mh) do { \
    _Pragma("unroll") \
    for (int _m = 0; _m < 4; ++_m) \
        _Pragma("unroll") \
        for (int _n = 0; _n < 4; ++_n) \
            acc[(mh) * 4 + _m][_n] = __builtin_amdgcn_mfma_f32_16x16x32_bf16( \
                af[_m], bfr[_n], acc[(mh) * 4 + _m][_n], 0, 0, 0); \
} while (0)

#define BARRIER() do { __builtin_amdgcn_s_barrier(); asm volatile("" ::: "memory"); } while (0)
#define VM4()    asm volatile("s_waitcnt vmcnt(4)" ::: "memory")
#define VM0()    asm volatile("s_waitcnt vmcnt(0)" ::: "memory")

// Even phase: af(mh0) + bf reads, stage, barrier, MFMA. ONE barrier.
#define PH_E(buf, kh, STG) do { \
    DS_AF(buf, kh, 0); DS_BF(buf, kh); \
    STG; \
    BARRIER(); \
    __builtin_amdgcn_s_setprio(1); MFMA16(0); __builtin_amdgcn_s_setprio(0); \
} while (0)

// Odd phase: af(mh1) read (bf reused), stage, optional vmcnt, barrier, MFMA.
#define PH_O(buf, kh, STG, WAIT) do { \
    DS_AF(buf, kh, 1); \
    STG; \
    WAIT; \
    BARRIER(); \
    __builtin_amdgcn_s_setprio(1); MFMA16(1); __builtin_amdgcn_s_setprio(0); \
} while (0)

    // Prologue: 6 pieces (12 loads): tile0 all 4 + tile1 kh0. Drain all but
    // the last 2 pieces (vmcnt(4)) -> buf0 kh0+kh1 valid through p3's drain.
    STAGE_P(0, 0, 0, 0); STAGE_P(0, 1, 0, 0);
    STAGE_P(0, 0, 1, 0); STAGE_P(0, 1, 1, 0);
    STAGE_P(1, 0, 0, 1); STAGE_P(1, 1, 0, 1);
    VM4();
    BARRIER();

#pragma unroll 1
    for (int i = 0; i < NT / 2 - 1; ++i) {
        const int t = 2 * i;
        PH_E(0, 0, STAGE_P(1, 0, 1, t + 1));
        PH_O(0, 0, STAGE_P(1, 1, 1, t + 1), (void)0);
        PH_E(0, 1, STAGE_P(0, 0, 0, t + 2));
        PH_O(0, 1, STAGE_P(0, 1, 0, t + 2), VM4());
        PH_E(1, 0, STAGE_P(0, 0, 1, t + 2));
        PH_O(1, 0, STAGE_P(0, 1, 1, t + 2), (void)0);
        PH_E(1, 1, STAGE_P(1, 0, 0, t + 3));
        PH_O(1, 1, STAGE_P(1, 1, 0, t + 3), VM4());
    }
    {   // Peel: t = NT-2. Only tile NT-1's kh1 still needs staging (p0/p1).
        PH_E(0, 0, STAGE_P(1, 0, 1, NT - 1));
        PH_O(0, 0, STAGE_P(1, 1, 1, NT - 1), (void)0);
        PH_E(0, 1, (void)0);
        PH_O(0, 1, (void)0, VM0());        // drain everything before buf1 reads
        PH_E(1, 0, (void)0);
        PH_O(1, 0, (void)0, (void)0);
        PH_E(1, 1, (void)0);
        {   // final phase: nothing to sync against
            DS_AF(1, 1, 1);
            __builtin_amdgcn_s_setprio(1); MFMA16(1); __builtin_amdgcn_s_setprio(0);
        }
    }

#undef PH_O
#undef PH_E
#undef VM0
#undef VM4
#undef BARRIER
#undef MFMA16
#undef DS_BF
#undef DS_AF
#undef STAGE_P
#undef GLDS

    // Epilogue: C/D layout col = lane&15, row = (lane>>4)*4 + j (verified R1-R5)
    const float s = scale_p[0];
#pragma unroll
    for (int n = 0; n < 4; ++n) {
        const int col = bn * 256 + wc * 64 + n * 16 + lr;
        const float bb = bias[col];
#pragma unroll
        for (int m = 0; m < 8; ++m) {
            const int row0 = bm * 256 + wr * 128 + m * 16 + (lane >> 4) * 4;
#pragma unroll
            for (int j = 0; j < 4; ++j)
                C[(size_t)(row0 + j) * N_DIM + col] = acc[m][n][j] * s + bb;
        }
    }
}

// Correctness-insurance fallback if ws_size < 64 MiB (should not trigger).
__global__ void naive_fallback(const float* __restrict__ x, const int* __restrict__ w,
                               const float* __restrict__ scale, const float* __restrict__ bias,
                               float* __restrict__ out) {
    size_t i = (size_t)blockIdx.x * blockDim.x + threadIdx.x;
    int m = (int)(i / N_DIM);
    int n = (int)(i % N_DIM);
    const float* xr = x + (size_t)m * K_DIM;
    const int*   wrw = w + (size_t)n * K_DIM;
    float acc = 0.f;
    for (int k = 0; k < K_DIM; ++k) acc += xr[k] * (float)wrw[k];
    out[i] = acc * scale[0] + bias[n];
}

extern "C" void kernel_launch(void* const* d_in, const int* in_sizes, int n_in,
                              void* d_out, int out_size, void* d_ws, size_t ws_size,
                              hipStream_t stream) {
    const float* x     = (const float*)d_in[0];
    const int*   qw    = (const int*)d_in[1];
    const float* scale = (const float*)d_in[2];
    const float* bias  = (const float*)d_in[3];
    float* out = (float*)d_out;

    const size_t elems = (size_t)M_DIM * K_DIM;          // 16,777,216
    const size_t need  = elems * 2u * sizeof(ushort);    // 64 MiB

    if (ws_size >= need) {
        ushort* xb = (ushort*)d_ws;
        ushort* wb = xb + elems;
        const int n4 = (int)(elems / 4);
        cvt_kernel<<<(2 * n4) / 256, 256, 0, stream>>>(x, qw, xb, wb, n4);
        dim3 grid(N_DIM / 256, M_DIM / 256);
        gemm_bf16_kernel<<<grid, 512, 0, stream>>>(xb, wb, scale, bias, out);
    } else {
        const size_t total = (size_t)M_DIM * N_DIM;
        naive_fallback<<<(int)(total / 256), 256, 0, stream>>>(x, qw, scale, bias, out);
    }
}